// Round 1
// baseline (687.544 us; speedup 1.0000x reference)
//
#include <hip/hip_runtime.h>

#define NV 30000
#define MP 32

__device__ __forceinline__ void build_x(float4 p, int m, int np,
                                        const float* __restrict__ vs,
                                        float cx, float cy, float cz,
                                        float* x /*13*/) {
    float msk = (m < np) ? 1.0f : 0.0f;
    float nrm = sqrtf(p.x*p.x + p.y*p.y + p.z*p.z);
    x[0] = p.x*msk; x[1] = p.y*msk; x[2] = p.z*msk; x[3] = p.w*msk;
    x[4] = (p.x - vs[0])*msk; x[5] = (p.y - vs[1])*msk; x[6] = (p.z - vs[2])*msk;
    x[7] = (p.x - cx)*msk; x[8] = (p.y - cy)*msk; x[9] = (p.z - cz)*msk;
    x[10] = nrm*msk;
    x[11] = vs[7]*msk;   // density
    x[12] = vs[6]*msk;   // mean dist
}

__global__ void k_init(double* __restrict__ stats) {
    int t = blockIdx.x*blockDim.x + threadIdx.x;
    if (t < 384) stats[t] = 0.0;
}

// Per-voxel reductions: points_mean (UNMASKED sum / num_points, per reference),
// masked vmean, mean masked dist, density. 1 thread per voxel.
__global__ void k_voxstats(const float* __restrict__ feats,
                           const int* __restrict__ npts,
                           float* __restrict__ vstat) {
    int n = blockIdx.x*blockDim.x + threadIdx.x;
    if (n >= NV) return;
    int np = npts[n];
    float fnp = (float)np;
    float safe = fmaxf(fnp, 1.0f);
    const float4* f4 = (const float4*)feats + (size_t)n*MP;
    float sx=0,sy=0,sz=0, mx=0,my=0,mz=0;
    for (int m=0;m<MP;++m) {
        float4 p = f4[m];
        sx+=p.x; sy+=p.y; sz+=p.z;
        if (m < np) { mx+=p.x; my+=p.y; mz+=p.z; }
    }
    float pmx = sx/fnp, pmy = sy/fnp, pmz = sz/fnp;
    float vmx = mx/safe, vmy = my/safe, vmz = mz/safe;
    float md = 0.f;
    for (int m=0;m<MP;++m) {
        float4 p = f4[m];
        if (m < np) {
            float dx=p.x-vmx, dy=p.y-vmy, dz=p.z-vmz;
            md += sqrtf(dx*dx+dy*dy+dz*dz);
        }
    }
    md /= safe;
    float dens = safe / 0.16f;   // VX*VY*VZ
    float* o = vstat + (size_t)n*8;
    o[0]=pmx;o[1]=pmy;o[2]=pmz;o[3]=vmx;o[4]=vmy;o[5]=vmz;o[6]=md;o[7]=dens;
}

// GEMM1 (13->64) + per-voxel raw min/max of h1 + global sum/sumsq (f64).
// Wave per voxel, lane = output channel. Block = 4 waves, grid-stride.
#define G1B 256
__global__ __launch_bounds__(256) void k_gemm1(
    const float* __restrict__ feats, const int* __restrict__ npts,
    const int* __restrict__ coors, const float* __restrict__ vstat,
    const float* __restrict__ W1,
    float* __restrict__ vmax1, float* __restrict__ vmin1,
    double* __restrict__ sum1, double* __restrict__ sumsq1)
{
    __shared__ float xls[4][MP][15];
    __shared__ double red[4][64];
    const int wave = threadIdx.x >> 6;
    const int lane = threadIdx.x & 63;
    float w1c[13];
    #pragma unroll
    for (int k=0;k<13;++k) w1c[k] = W1[k*64 + lane];
    double dsum = 0.0, dsq = 0.0;
    const int iters = (NV + G1B*4 - 1) / (G1B*4);
    for (int it=0; it<iters; ++it) {
        int n = (it*G1B + blockIdx.x)*4 + wave;
        bool act = (n < NV);
        if (act && lane < MP) {
            int np = npts[n];
            float cx = (float)coors[n*4+3]*0.2f + 0.1f;
            float cy = (float)coors[n*4+2]*0.2f - 39.9f;
            float cz = (float)coors[n*4+1]*4.0f - 1.0f;
            const float* vs = vstat + (size_t)n*8;
            float4 p = ((const float4*)feats)[(size_t)n*MP + lane];
            float xv[13];
            build_x(p, lane, np, vs, cx, cy, cz, xv);
            #pragma unroll
            for (int k=0;k<13;++k) xls[wave][lane][k] = xv[k];
        }
        __syncthreads();
        if (act) {
            float hmax = -3.402823466e38f, hmin = 3.402823466e38f;
            float lsum = 0.f, lsq = 0.f;
            #pragma unroll 4
            for (int m=0;m<MP;++m) {
                float h = 0.f;
                #pragma unroll
                for (int k=0;k<13;++k) h = fmaf(xls[wave][m][k], w1c[k], h);
                hmax = fmaxf(hmax, h); hmin = fminf(hmin, h);
                lsum += h; lsq = fmaf(h, h, lsq);
            }
            vmax1[(size_t)n*64 + lane] = hmax;
            vmin1[(size_t)n*64 + lane] = hmin;
            dsum += (double)lsum; dsq += (double)lsq;
        }
        __syncthreads();
    }
    red[wave][lane] = dsum;
    __syncthreads();
    if (wave == 0) {
        double s = red[0][lane]+red[1][lane]+red[2][lane]+red[3][lane];
        atomicAdd(&sum1[lane], s);
    }
    __syncthreads();
    red[wave][lane] = dsq;
    __syncthreads();
    if (wave == 0) {
        double s = red[0][lane]+red[1][lane]+red[2][lane]+red[3][lane];
        atomicAdd(&sumsq1[lane], s);
    }
}

__global__ void k_fin1(const double* __restrict__ sum1, const double* __restrict__ sumsq1,
                       const float* __restrict__ g1, const float* __restrict__ b1,
                       float* __restrict__ sc1, float* __restrict__ sh1) {
    int c = threadIdx.x;
    if (c >= 64) return;
    double cnt = (double)NV * MP;
    double mu = sum1[c]/cnt;
    double var = sumsq1[c]/cnt - mu*mu;
    double rs = 1.0 / sqrt(var + 1e-3);
    double sc = (double)g1[c]*rs;
    sc1[c] = (float)sc;
    sh1[c] = (float)((double)b1[c] - mu*sc);
}

// agg1[n,c] = relu(affine(max-or-min(h1))) — monotone trick.
__global__ void k_agg1(const float* __restrict__ vmax1, const float* __restrict__ vmin1,
                       const float* __restrict__ sc1, const float* __restrict__ sh1,
                       float* __restrict__ agg1) {
    int t = blockIdx.x*blockDim.x + threadIdx.x;
    if (t >= NV*64) return;
    int c = t & 63;
    float s = sc1[c];
    float v = (s >= 0.f) ? vmax1[t] : vmin1[t];
    agg1[t] = fmaxf(fmaf(v, s, sh1[c]), 0.f);
}

// GEMM2: rebuild x -> h1 -> bn/relu -> x2 (128ch, in LDS transposed) -> @W2(LDS).
// 512 thr, tile = 4 voxels (128 pts) x 128 ch, 4x8 register tile/thread.
// Tracks per-voxel min/max of raw h2 + global f64 sum/sumsq.
#define G2B 256
__global__ __launch_bounds__(512) void k_gemm2(
    const float* __restrict__ feats, const int* __restrict__ npts,
    const int* __restrict__ coors, const float* __restrict__ vstat,
    const float* __restrict__ W1, const float* __restrict__ W2,
    const float* __restrict__ sc1, const float* __restrict__ sh1,
    const float* __restrict__ agg1,
    float* __restrict__ vmax2, float* __restrict__ vmin2,
    double* __restrict__ sum2, double* __restrict__ sumsq2)
{
    __shared__ float w2s[128][128];   // 64 KB
    __shared__ float x2T[128][132];   // 67.6 KB  (k-major, padded: A-reads are b128)
    __shared__ float xls[128][15];    // 7.5 KB
    __shared__ float w1s[13][64];     // 3.3 KB
    __shared__ float aggls[256];
    __shared__ float sc1s[64], sh1s[64];

    const int t = threadIdx.x;
    for (int i = t; i < 128*128/4; i += 512)
        ((float4*)w2s)[i] = ((const float4*)W2)[i];
    for (int i = t; i < 13*64; i += 512)
        ((float*)w1s)[i] = W1[i];
    if (t < 64) { sc1s[t] = sc1[t]; sh1s[t] = sh1[t]; }

    const int tr = t & 31;    // point group: points tr*4 .. tr*4+3
    const int tc = t >> 5;    // 0..15: channels tc*8 .. tc*8+7
    double dsum[8], dsq[8];
    #pragma unroll
    for (int j=0;j<8;++j) { dsum[j]=0.0; dsq[j]=0.0; }

    const int iters = (NV/4 + G2B - 1) / G2B;
    __syncthreads();
    for (int it=0; it<iters; ++it) {
        int bv = (it*G2B + blockIdx.x)*4;     // base voxel (block-uniform)
        bool act = (bv < NV);
        if (act) {
            if (t < 256) aggls[t] = agg1[(size_t)bv*64 + t];
            if (t < 128) {
                int p = t; int n = bv + (p>>5); int m = p & 31;
                int np = npts[n];
                float cx = (float)coors[n*4+3]*0.2f + 0.1f;
                float cy = (float)coors[n*4+2]*0.2f - 39.9f;
                float cz = (float)coors[n*4+1]*4.0f - 1.0f;
                const float* vs = vstat + (size_t)n*8;
                float4 pt = ((const float4*)feats)[(size_t)n*MP + m];
                float xv[13];
                build_x(pt, m, np, vs, cx, cy, cz, xv);
                #pragma unroll
                for (int k=0;k<13;++k) xls[p][k] = xv[k];
            }
        }
        __syncthreads();
        if (act) {
            // h1 + BN1 + ReLU, fill x2T rows [c][p] and agg rows [64+c][p]
            int p = t & 127, cg = t >> 7;     // cg in 0..3
            float xr[13];
            #pragma unroll
            for (int k=0;k<13;++k) xr[k] = xls[p][k];
            int vb = (p >> 5) << 6;
            #pragma unroll
            for (int j=0;j<16;++j) {
                int c = cg*16 + j;
                float h = 0.f;
                #pragma unroll
                for (int k=0;k<13;++k) h = fmaf(xr[k], w1s[k][c], h);
                float a = fmaxf(fmaf(h, sc1s[c], sh1s[c]), 0.f);
                x2T[c][p] = a;
                x2T[64+c][p] = aggls[vb + c];
            }
        }
        __syncthreads();
        if (act) {
            float acc[32];
            #pragma unroll
            for (int i=0;i<32;++i) acc[i] = 0.f;
            #pragma unroll 4
            for (int k=0;k<128;++k) {
                float4 av  = *(const float4*)&x2T[k][tr<<2];
                float4 b0  = *(const float4*)&w2s[k][tc<<3];
                float4 b1v = *(const float4*)&w2s[k][(tc<<3)+4];
                float bb[8] = {b0.x,b0.y,b0.z,b0.w,b1v.x,b1v.y,b1v.z,b1v.w};
                #pragma unroll
                for (int j=0;j<8;++j) {
                    acc[0*8+j] = fmaf(av.x, bb[j], acc[0*8+j]);
                    acc[1*8+j] = fmaf(av.y, bb[j], acc[1*8+j]);
                    acc[2*8+j] = fmaf(av.z, bb[j], acc[2*8+j]);
                    acc[3*8+j] = fmaf(av.w, bb[j], acc[3*8+j]);
                }
            }
            int vox = bv + (tr >> 3);
            #pragma unroll
            for (int j=0;j<8;++j) {
                float mx = fmaxf(fmaxf(acc[j],acc[8+j]), fmaxf(acc[16+j],acc[24+j]));
                float mn = fminf(fminf(acc[j],acc[8+j]), fminf(acc[16+j],acc[24+j]));
                #pragma unroll
                for (int off=1; off<8; off<<=1) {
                    mx = fmaxf(mx, __shfl_xor(mx, off));
                    mn = fminf(mn, __shfl_xor(mn, off));
                }
                if ((tr & 7) == 0) {
                    vmax2[(size_t)vox*128 + (tc<<3) + j] = mx;
                    vmin2[(size_t)vox*128 + (tc<<3) + j] = mn;
                }
                float ls = acc[j]+acc[8+j]+acc[16+j]+acc[24+j];
                float lq = fmaf(acc[j],acc[j], fmaf(acc[8+j],acc[8+j],
                           fmaf(acc[16+j],acc[16+j], acc[24+j]*acc[24+j])));
                dsum[j] += (double)ls; dsq[j] += (double)lq;
            }
        }
        __syncthreads();
    }
    // reduce stats across the 32-lane (tr) group; (tc,j) owns channel uniquely
    #pragma unroll
    for (int j=0;j<8;++j) {
        double s = dsum[j], q = dsq[j];
        for (int off=1; off<32; off<<=1) {
            s += __shfl_xor(s, off);
            q += __shfl_xor(q, off);
        }
        if (tr == 0) {
            atomicAdd(&sum2[(tc<<3)+j], s);
            atomicAdd(&sumsq2[(tc<<3)+j], q);
        }
    }
}

__global__ void k_fin2(const double* __restrict__ sum2, const double* __restrict__ sumsq2,
                       const float* __restrict__ g2, const float* __restrict__ b2,
                       float* __restrict__ sc2, float* __restrict__ sh2) {
    int c = threadIdx.x;
    if (c >= 128) return;
    double cnt = (double)NV * MP;
    double mu = sum2[c]/cnt;
    double var = sumsq2[c]/cnt - mu*mu;
    double rs = 1.0 / sqrt(var + 1e-3);
    double sc = (double)g2[c]*rs;
    sc2[c] = (float)sc;
    sh2[c] = (float)((double)b2[c] - mu*sc);
}

__global__ void k_out(const float* __restrict__ vmax2, const float* __restrict__ vmin2,
                      const float* __restrict__ sc2, const float* __restrict__ sh2,
                      float* __restrict__ out) {
    int t = blockIdx.x*blockDim.x + threadIdx.x;
    if (t >= NV*128) return;
    int c = t & 127;
    float s = sc2[c];
    float v = (s >= 0.f) ? vmax2[t] : vmin2[t];
    out[t] = fmaxf(fmaf(v, s, sh2[c]), 0.f);
}

extern "C" void kernel_launch(void* const* d_in, const int* in_sizes, int n_in,
                              void* d_out, int out_size, void* d_ws, size_t ws_size,
                              hipStream_t stream) {
    const float* feats = (const float*)d_in[0];
    const int*   npts  = (const int*)d_in[1];
    const int*   coors = (const int*)d_in[2];
    const float* W1    = (const float*)d_in[3];
    const float* g1    = (const float*)d_in[4];
    const float* b1    = (const float*)d_in[5];
    const float* W2    = (const float*)d_in[6];
    const float* g2    = (const float*)d_in[7];
    const float* b2    = (const float*)d_in[8];
    float* out = (float*)d_out;

    // workspace layout (f64 stats first for alignment)
    double* sum1   = (double*)d_ws;            // 64
    double* sumsq1 = sum1 + 64;                // 64
    double* sum2   = sumsq1 + 64;              // 128
    double* sumsq2 = sum2 + 128;               // 128  (384 doubles total)
    float* fb = (float*)(sumsq2 + 128);
    float* vstat = fb;            fb += (size_t)NV*8;
    float* vmax1 = fb;            fb += (size_t)NV*64;
    float* vmin1 = fb;            fb += (size_t)NV*64;
    float* agg1  = fb;            fb += (size_t)NV*64;
    float* vmax2 = fb;            fb += (size_t)NV*128;
    float* vmin2 = fb;            fb += (size_t)NV*128;
    float* sc1 = fb;              fb += 64;
    float* sh1 = fb;              fb += 64;
    float* sc2 = fb;              fb += 128;
    float* sh2 = fb;              fb += 128;

    hipLaunchKernelGGL(k_init, dim3(1), dim3(384), 0, stream, sum1);
    hipLaunchKernelGGL(k_voxstats, dim3((NV+255)/256), dim3(256), 0, stream,
                       feats, npts, vstat);
    hipLaunchKernelGGL(k_gemm1, dim3(G1B), dim3(256), 0, stream,
                       feats, npts, coors, vstat, W1, vmax1, vmin1, sum1, sumsq1);
    hipLaunchKernelGGL(k_fin1, dim3(1), dim3(64), 0, stream,
                       sum1, sumsq1, g1, b1, sc1, sh1);
    hipLaunchKernelGGL(k_agg1, dim3(NV*64/256), dim3(256), 0, stream,
                       vmax1, vmin1, sc1, sh1, agg1);
    hipLaunchKernelGGL(k_gemm2, dim3(G2B), dim3(512), 0, stream,
                       feats, npts, coors, vstat, W1, W2, sc1, sh1, agg1,
                       vmax2, vmin2, sum2, sumsq2);
    hipLaunchKernelGGL(k_fin2, dim3(1), dim3(128), 0, stream,
                       sum2, sumsq2, g2, b2, sc2, sh2);
    hipLaunchKernelGGL(k_out, dim3(NV*128/256), dim3(256), 0, stream,
                       vmax2, vmin2, sc2, sh2, out);
}

// Round 4
// 315.048 us; speedup vs baseline: 2.1823x; 2.1823x over previous
//
#include <hip/hip_runtime.h>

#define NV 30000
#define MP 32
#define NB2 512
#define IT2 30

typedef short          s16x8 __attribute__((ext_vector_type(8)));
typedef unsigned short u16x4 __attribute__((ext_vector_type(4)));
typedef float          f32x4 __attribute__((ext_vector_type(4)));

// f32 -> bf16 (round-to-nearest-even), bit-exact with v_cvt for finite values
__device__ __forceinline__ unsigned short bf16h(float f) {
    unsigned int u = __float_as_uint(f);
    return (unsigned short)((u + 0x7FFFu + ((u >> 16) & 1u)) >> 16);
}
__device__ __forceinline__ float bf16f(unsigned short h) {
    return __uint_as_float(((unsigned int)h) << 16);
}

__global__ void k_init(double* __restrict__ stats) {
    int t = blockIdx.x*blockDim.x + threadIdx.x;
    if (t < 384) stats[t] = 0.0;
}

// Per-voxel reductions: points_mean (UNMASKED sum / num_points, per reference),
// masked vmean, mean masked dist, density. 1 thread per voxel.
__global__ void k_voxstats(const float* __restrict__ feats,
                           const int* __restrict__ npts,
                           float* __restrict__ vstat) {
    int n = blockIdx.x*blockDim.x + threadIdx.x;
    if (n >= NV) return;
    int np = npts[n];
    float fnp = (float)np;
    float safe = fmaxf(fnp, 1.0f);
    const float4* f4 = (const float4*)feats + (size_t)n*MP;
    float sx=0,sy=0,sz=0, mx=0,my=0,mz=0;
    for (int m=0;m<MP;++m) {
        float4 p = f4[m];
        sx+=p.x; sy+=p.y; sz+=p.z;
        if (m < np) { mx+=p.x; my+=p.y; mz+=p.z; }
    }
    float pmx = sx/fnp, pmy = sy/fnp, pmz = sz/fnp;
    float vmx = mx/safe, vmy = my/safe, vmz = mz/safe;
    float md = 0.f;
    for (int m=0;m<MP;++m) {
        float4 p = f4[m];
        if (m < np) {
            float dx=p.x-vmx, dy=p.y-vmy, dz=p.z-vmz;
            md += sqrtf(dx*dx+dy*dy+dz*dz);
        }
    }
    md /= safe;
    float dens = safe / 0.16f;   // VX*VY*VZ
    float* o = vstat + (size_t)n*8;
    o[0]=pmx;o[1]=pmy;o[2]=pmz;o[3]=vmx;o[4]=vmy;o[5]=vmz;o[6]=md;o[7]=dens;
}

// GEMM1 (13->64) + per-voxel raw min/max of h1 + global sum/sumsq (f64).
// Wave per voxel, lane = output channel. 1024 blocks -> 4 blocks/CU (latency hiding).
#define G1B 1024
__global__ __launch_bounds__(256) void k_gemm1(
    const float* __restrict__ feats, const int* __restrict__ npts,
    const int* __restrict__ coors, const float* __restrict__ vstat,
    const float* __restrict__ W1,
    float* __restrict__ vmax1, float* __restrict__ vmin1,
    double* __restrict__ sum1, double* __restrict__ sumsq1)
{
    __shared__ float xls[4][MP][15];
    __shared__ double red[4][64];
    const int wave = threadIdx.x >> 6;
    const int lane = threadIdx.x & 63;
    float w1c[13];
    #pragma unroll
    for (int k=0;k<13;++k) w1c[k] = W1[k*64 + lane];
    double dsum = 0.0, dsq = 0.0;
    const int iters = (NV + G1B*4 - 1) / (G1B*4);
    for (int it=0; it<iters; ++it) {
        int n = (it*G1B + blockIdx.x)*4 + wave;
        bool act = (n < NV);
        if (act && lane < MP) {
            int np = npts[n];
            float cx = (float)coors[n*4+3]*0.2f + 0.1f;
            float cy = (float)coors[n*4+2]*0.2f - 39.9f;
            float cz = (float)coors[n*4+1]*4.0f - 1.0f;
            const float* vs = vstat + (size_t)n*8;
            float4 p = ((const float4*)feats)[(size_t)n*MP + lane];
            float msk = (lane < np) ? 1.0f : 0.0f;
            float xv[13];
            xv[0]=p.x*msk; xv[1]=p.y*msk; xv[2]=p.z*msk; xv[3]=p.w*msk;
            xv[4]=(p.x-vs[0])*msk; xv[5]=(p.y-vs[1])*msk; xv[6]=(p.z-vs[2])*msk;
            xv[7]=(p.x-cx)*msk; xv[8]=(p.y-cy)*msk; xv[9]=(p.z-cz)*msk;
            xv[10]=sqrtf(p.x*p.x+p.y*p.y+p.z*p.z)*msk;
            xv[11]=vs[7]*msk; xv[12]=vs[6]*msk;
            #pragma unroll
            for (int k=0;k<13;++k) xls[wave][lane][k] = xv[k];
        }
        __syncthreads();
        if (act) {
            float hmax = -3.402823466e38f, hmin = 3.402823466e38f;
            float lsum = 0.f, lsq = 0.f;
            #pragma unroll 4
            for (int m=0;m<MP;++m) {
                float h = 0.f;
                #pragma unroll
                for (int k=0;k<13;++k) h = fmaf(xls[wave][m][k], w1c[k], h);
                hmax = fmaxf(hmax, h); hmin = fminf(hmin, h);
                lsum += h; lsq = fmaf(h, h, lsq);
            }
            vmax1[(size_t)n*64 + lane] = hmax;
            vmin1[(size_t)n*64 + lane] = hmin;
            dsum += (double)lsum; dsq += (double)lsq;
        }
        __syncthreads();
    }
    red[wave][lane] = dsum;
    __syncthreads();
    if (wave == 0) {
        double s = red[0][lane]+red[1][lane]+red[2][lane]+red[3][lane];
        atomicAdd(&sum1[lane], s);
    }
    __syncthreads();
    red[wave][lane] = dsq;
    __syncthreads();
    if (wave == 0) {
        double s = red[0][lane]+red[1][lane]+red[2][lane]+red[3][lane];
        atomicAdd(&sumsq1[lane], s);
    }
}

__global__ void k_fin1(const double* __restrict__ sum1, const double* __restrict__ sumsq1,
                       const float* __restrict__ g1, const float* __restrict__ b1,
                       float* __restrict__ sc1, float* __restrict__ sh1) {
    int c = threadIdx.x;
    if (c >= 64) return;
    double cnt = (double)NV * MP;
    double mu = sum1[c]/cnt;
    double var = sumsq1[c]/cnt - mu*mu;
    double rs = 1.0 / sqrt(var + 1e-3);
    double sc = (double)g1[c]*rs;
    sc1[c] = (float)sc;
    sh1[c] = (float)((double)b1[c] - mu*sc);
}

// ---------------------------------------------------------------------------
// GEMM2 via MFMA bf16 hi/lo 3-pass split (short8 fragments, no __bf16 type).
// Block: 256 thr (4 waves). Tile: 2 voxels (M=64) x N=128, K=128.
// Wave w owns N-slice [w*32, w*32+32): W2 hi/lo fragments in registers.
// A (x2) staged in LDS as hi/lo ushort planes, XOR-swizzled (idx ^= (p&7)<<3)
// so stride-256B ds_read_b128 A-frag reads are <=2-way conflict.
// Stage phase: thread owns 4 rows x 4 channels, W1 in 52 VGPRs, zero LDS reads.
// agg1 computed inline from vmax1/vmin1 (monotone BN+relu trick).
// ---------------------------------------------------------------------------
__global__ __launch_bounds__(256, 2) void k_gemm2(
    const float* __restrict__ feats, const int* __restrict__ npts,
    const int* __restrict__ coors, const float* __restrict__ vstat,
    const float* __restrict__ W1, const float* __restrict__ W2,
    const float* __restrict__ sc1, const float* __restrict__ sh1,
    const float* __restrict__ vmax1, const float* __restrict__ vmin1,
    float* __restrict__ vmax2, float* __restrict__ vmin2,
    double* __restrict__ sum2, double* __restrict__ sumsq2)
{
    __shared__ unsigned short x2h[64*128];
    __shared__ unsigned short x2l[64*128];

    const int t = threadIdx.x;
    const int lane = t & 63;
    const int w = t >> 6;

    // ---- B fragments (W2) hi/lo in registers: Bh/Bl[nt][ks] ----
    s16x8 Bh[2][4], Bl[2][4];
    {
        const int col0 = w*32 + (lane & 15);
        const int kq   = (lane >> 4) << 3;
        #pragma unroll
        for (int nt=0; nt<2; ++nt)
            #pragma unroll
            for (int ks=0; ks<4; ++ks)
                #pragma unroll
                for (int j=0; j<8; ++j) {
                    float v = W2[(ks*32 + kq + j)*128 + col0 + nt*16];
                    unsigned short h = bf16h(v);
                    Bh[nt][ks][j] = (short)h;
                    Bl[nt][ks][j] = (short)bf16h(v - bf16f(h));
                }
    }

    const int cq = t & 15;   // channels cq*4 .. +3
    const int rq = t >> 4;   // rows     rq*4 .. +3
    float w1r[13][4];
    #pragma unroll
    for (int k=0;k<13;++k) {
        const float4 v = *(const float4*)&W1[k*64 + cq*4];
        w1r[k][0]=v.x; w1r[k][1]=v.y; w1r[k][2]=v.z; w1r[k][3]=v.w;
    }
    const float4 scv = *(const float4*)&sc1[cq*4];
    const float4 shv = *(const float4*)&sh1[cq*4];
    const float scs[4] = {scv.x,scv.y,scv.z,scv.w};
    const float shs[4] = {shv.x,shv.y,shv.z,shv.w};

    double dsum[2] = {0.0,0.0}, dsq[2] = {0.0,0.0};

    for (int it=0; it<IT2; ++it) {
        const int pair = it*NB2 + blockIdx.x;   // block-uniform
        const bool act = (pair < NV/2);
        const int vox0 = pair*2;

        // ---- stage phase: build x2 hi/lo into LDS (no LDS reads) ----
        if (act) {
            const int vox = vox0 + (rq >> 3);
            const int np = npts[vox];
            const float cx = (float)coors[vox*4+3]*0.2f + 0.1f;
            const float cy = (float)coors[vox*4+2]*0.2f - 39.9f;
            const float cz = (float)coors[vox*4+1]*4.0f - 1.0f;
            const float4 vsa = *(const float4*)&vstat[(size_t)vox*8];
            const float4 vsb = *(const float4*)&vstat[(size_t)vox*8+4];
            // agg on the fly: relu(sc * (sc>=0 ? vmax1 : vmin1) + sh)
            const float4 mx4 = *(const float4*)&vmax1[(size_t)vox*64 + cq*4];
            const float4 mn4 = *(const float4*)&vmin1[(size_t)vox*64 + cq*4];
            u16x4 agh, agl;
            {
                const float mxv[4] = {mx4.x,mx4.y,mx4.z,mx4.w};
                const float mnv[4] = {mn4.x,mn4.y,mn4.z,mn4.w};
                #pragma unroll
                for (int cc=0;cc<4;++cc) {
                    float v = (scs[cc] >= 0.f) ? mxv[cc] : mnv[cc];
                    float a = fmaxf(fmaf(v, scs[cc], shs[cc]), 0.f);
                    unsigned short h = bf16h(a);
                    agh[cc] = h; agl[cc] = bf16h(a - bf16f(h));
                }
            }
            #pragma unroll
            for (int rr=0; rr<4; ++rr) {
                const int p = rq*4 + rr;
                const int m = p & 31;
                const float4 pt = ((const float4*)feats)[(size_t)vox*MP + m];
                const float msk = (m < np) ? 1.0f : 0.0f;
                float xv[13];
                xv[0]=pt.x*msk; xv[1]=pt.y*msk; xv[2]=pt.z*msk; xv[3]=pt.w*msk;
                xv[4]=(pt.x-vsa.x)*msk; xv[5]=(pt.y-vsa.y)*msk; xv[6]=(pt.z-vsa.z)*msk;
                xv[7]=(pt.x-cx)*msk; xv[8]=(pt.y-cy)*msk; xv[9]=(pt.z-cz)*msk;
                xv[10]=sqrtf(pt.x*pt.x+pt.y*pt.y+pt.z*pt.z)*msk;
                xv[11]=vsb.w*msk; xv[12]=vsb.z*msk;
                u16x4 hh, hl;
                #pragma unroll
                for (int cc=0;cc<4;++cc) {
                    float h = 0.f;
                    #pragma unroll
                    for (int k=0;k<13;++k) h = fmaf(xv[k], w1r[k][cc], h);
                    float a = fmaxf(fmaf(h, scs[cc], shs[cc]), 0.f);
                    unsigned short ah = bf16h(a);
                    hh[cc] = ah; hl[cc] = bf16h(a - bf16f(ah));
                }
                const int sw = (p & 7) << 3;     // 16B-granular XOR swizzle
                const int b  = p*128;
                *(u16x4*)&x2h[(b + cq*4)      ^ sw] = hh;
                *(u16x4*)&x2l[(b + cq*4)      ^ sw] = hl;
                *(u16x4*)&x2h[(b + 64 + cq*4) ^ sw] = agh;
                *(u16x4*)&x2l[(b + 64 + cq*4) ^ sw] = agl;
            }
        }
        __syncthreads();

        // ---- MFMA phase: 96 mfma_f32_16x16x32_bf16 per wave ----
        f32x4 acc[4][2];
        if (act) {
            #pragma unroll
            for (int mt=0;mt<4;++mt)
                #pragma unroll
                for (int nt=0;nt<2;++nt) {
                    acc[mt][nt][0]=0.f; acc[mt][nt][1]=0.f;
                    acc[mt][nt][2]=0.f; acc[mt][nt][3]=0.f;
                }
            const int lrow = lane & 15;
            const int lk   = (lane >> 4) << 3;
            #pragma unroll
            for (int ks=0; ks<4; ++ks) {
                s16x8 Ah[4], Al[4];
                #pragma unroll
                for (int mt=0;mt<4;++mt) {
                    const int p = mt*16 + lrow;
                    const int idx = (p*128 + ks*32 + lk) ^ ((p & 7) << 3);
                    Ah[mt] = *(const s16x8*)&x2h[idx];
                    Al[mt] = *(const s16x8*)&x2l[idx];
                }
                #pragma unroll
                for (int mt=0;mt<4;++mt)
                    #pragma unroll
                    for (int nt=0;nt<2;++nt) {
                        acc[mt][nt] = __builtin_amdgcn_mfma_f32_16x16x32_bf16(Ah[mt], Bh[nt][ks], acc[mt][nt], 0,0,0);
                        acc[mt][nt] = __builtin_amdgcn_mfma_f32_16x16x32_bf16(Al[mt], Bh[nt][ks], acc[mt][nt], 0,0,0);
                        acc[mt][nt] = __builtin_amdgcn_mfma_f32_16x16x32_bf16(Ah[mt], Bl[nt][ks], acc[mt][nt], 0,0,0);
                    }
            }
        }
        __syncthreads();   // A reads done; next iter may overwrite LDS

        // ---- epilogue: per-voxel max/min (C/D layout: col=lane&15, row=(lane>>4)*4+r) ----
        if (act) {
            #pragma unroll
            for (int v=0; v<2; ++v) {
                #pragma unroll
                for (int nt=0; nt<2; ++nt) {
                    float mx = acc[2*v][nt][0], mn = acc[2*v][nt][0];
                    #pragma unroll
                    for (int r=1;r<4;++r) { mx = fmaxf(mx, acc[2*v][nt][r]); mn = fminf(mn, acc[2*v][nt][r]); }
                    #pragma unroll
                    for (int r=0;r<4;++r) { mx = fmaxf(mx, acc[2*v+1][nt][r]); mn = fminf(mn, acc[2*v+1][nt][r]); }
                    mx = fmaxf(mx, __shfl_xor(mx, 16)); mn = fminf(mn, __shfl_xor(mn, 16));
                    mx = fmaxf(mx, __shfl_xor(mx, 32)); mn = fminf(mn, __shfl_xor(mn, 32));
                    if (lane < 16) {
                        const size_t o = (size_t)(vox0 + v)*128 + w*32 + nt*16 + lane;
                        vmax2[o] = mx; vmin2[o] = mn;
                    }
                }
            }
            #pragma unroll
            for (int nt=0; nt<2; ++nt) {
                float s = 0.f, q = 0.f;
                #pragma unroll
                for (int mt=0;mt<4;++mt)
                    #pragma unroll
                    for (int r=0;r<4;++r) { s += acc[mt][nt][r]; q = fmaf(acc[mt][nt][r], acc[mt][nt][r], q); }
                dsum[nt] += (double)s; dsq[nt] += (double)q;
            }
        }
    }

    // ---- global BN2 stats: butterfly over row-groups, then f64 atomics ----
    #pragma unroll
    for (int nt=0; nt<2; ++nt) {
        double s = dsum[nt], q = dsq[nt];
        s += __shfl_xor(s, 16); q += __shfl_xor(q, 16);
        s += __shfl_xor(s, 32); q += __shfl_xor(q, 32);
        if (lane < 16) {
            atomicAdd(&sum2[w*32 + nt*16 + lane], s);
            atomicAdd(&sumsq2[w*32 + nt*16 + lane], q);
        }
    }
}

__global__ void k_fin2(const double* __restrict__ sum2, const double* __restrict__ sumsq2,
                       const float* __restrict__ g2, const float* __restrict__ b2,
                       float* __restrict__ sc2, float* __restrict__ sh2) {
    int c = threadIdx.x;
    if (c >= 128) return;
    double cnt = (double)NV * MP;
    double mu = sum2[c]/cnt;
    double var = sumsq2[c]/cnt - mu*mu;
    double rs = 1.0 / sqrt(var + 1e-3);
    double sc = (double)g2[c]*rs;
    sc2[c] = (float)sc;
    sh2[c] = (float)((double)b2[c] - mu*sc);
}

__global__ void k_out(const float* __restrict__ vmax2, const float* __restrict__ vmin2,
                      const float* __restrict__ sc2, const float* __restrict__ sh2,
                      float* __restrict__ out) {
    int t = blockIdx.x*blockDim.x + threadIdx.x;
    if (t >= NV*128) return;
    int c = t & 127;
    float s = sc2[c];
    float v = (s >= 0.f) ? vmax2[t] : vmin2[t];
    out[t] = fmaxf(fmaf(v, s, sh2[c]), 0.f);
}

extern "C" void kernel_launch(void* const* d_in, const int* in_sizes, int n_in,
                              void* d_out, int out_size, void* d_ws, size_t ws_size,
                              hipStream_t stream) {
    const float* feats = (const float*)d_in[0];
    const int*   npts  = (const int*)d_in[1];
    const int*   coors = (const int*)d_in[2];
    const float* W1    = (const float*)d_in[3];
    const float* g1    = (const float*)d_in[4];
    const float* b1    = (const float*)d_in[5];
    const float* W2    = (const float*)d_in[6];
    const float* g2    = (const float*)d_in[7];
    const float* b2    = (const float*)d_in[8];
    float* out = (float*)d_out;

    double* sum1   = (double*)d_ws;            // 64
    double* sumsq1 = sum1 + 64;                // 64
    double* sum2   = sumsq1 + 64;              // 128
    double* sumsq2 = sum2 + 128;               // 128  (384 doubles total)
    float* fb = (float*)(sumsq2 + 128);
    float* vstat = fb;            fb += (size_t)NV*8;
    float* vmax1 = fb;            fb += (size_t)NV*64;
    float* vmin1 = fb;            fb += (size_t)NV*64;
    float* vmax2 = fb;            fb += (size_t)NV*128;
    float* vmin2 = fb;            fb += (size_t)NV*128;
    float* sc1 = fb;              fb += 64;
    float* sh1 = fb;              fb += 64;
    float* sc2 = fb;              fb += 128;
    float* sh2 = fb;              fb += 128;

    hipLaunchKernelGGL(k_init, dim3(1), dim3(384), 0, stream, sum1);
    hipLaunchKernelGGL(k_voxstats, dim3((NV+255)/256), dim3(256), 0, stream,
                       feats, npts, vstat);
    hipLaunchKernelGGL(k_gemm1, dim3(G1B), dim3(256), 0, stream,
                       feats, npts, coors, vstat, W1, vmax1, vmin1, sum1, sumsq1);
    hipLaunchKernelGGL(k_fin1, dim3(1), dim3(64), 0, stream,
                       sum1, sumsq1, g1, b1, sc1, sh1);
    hipLaunchKernelGGL(k_gemm2, dim3(NB2), dim3(256), 0, stream,
                       feats, npts, coors, vstat, W1, W2, sc1, sh1, vmax1, vmin1,
                       vmax2, vmin2, sum2, sumsq2);
    hipLaunchKernelGGL(k_fin2, dim3(1), dim3(128), 0, stream,
                       sum2, sumsq2, g2, b2, sc2, sh2);
    hipLaunchKernelGGL(k_out, dim3(NV*128/256), dim3(256), 0, stream,
                       vmax2, vmin2, sc2, sh2, out);
}